// Round 2
// baseline (104.572 us; speedup 1.0000x reference)
//
#include <hip/hip_runtime.h>
#include <hip/hip_bf16.h>

#define LP   640
#define LC   128
#define NODE 128
#define HID  32
#define PAIR 128
#define EPS  1e-5f

typedef __bf16 bf16_t;
typedef __attribute__((ext_vector_type(8))) __bf16 bf16x8;
typedef __attribute__((ext_vector_type(4))) float f32x4;

// ---------------- K1: LayerNorm + projection per row, plus mask output ----------------
// blocks 0..639: p rows; 640..767: c rows; 768..1087: mask writes (256 elems each)
__global__ __launch_bounds__(128) void k1_rows(
    const float* __restrict__ p_embed, const float* __restrict__ c_embed,
    const int* __restrict__ p_mask, const int* __restrict__ c_mask,
    const float* __restrict__ ln_p_w, const float* __restrict__ ln_p_b,
    const float* __restrict__ ln_c_w, const float* __restrict__ ln_c_b,
    const float* __restrict__ W_p, const float* __restrict__ b_p,
    const float* __restrict__ W_c, const float* __restrict__ b_c,
    bf16_t* __restrict__ p_out, bf16_t* __restrict__ c_out,
    float* __restrict__ mask_out)
{
    const int blk = blockIdx.x;
    const int t = threadIdx.x;

    if (blk >= LP + LC) {
        // mask blocks: 320 blocks x 256 elems = 81920 = LP*LC
        int base = (blk - (LP + LC)) * 256;
        #pragma unroll
        for (int u = 0; u < 2; ++u) {
            int idx = base + u * 128 + t;
            int i = idx >> 7, j = idx & 127;
            mask_out[idx] = (p_mask[i] != 0 && c_mask[j] != 0) ? 1.0f : 0.0f;
        }
        return;
    }

    const float* x; const float* lw; const float* lb;
    const float* W; const float* bb; bf16_t* yo;
    if (blk < LP) {
        x = p_embed + blk * NODE; lw = ln_p_w; lb = ln_p_b;
        W = W_p; bb = b_p; yo = p_out + blk * HID;
    } else {
        int row = blk - LP;
        x = c_embed + row * NODE; lw = ln_c_w; lb = ln_c_b;
        W = W_c; bb = b_c; yo = c_out + row * HID;
    }

    __shared__ __align__(16) float sx[NODE];
    __shared__ __align__(16) float red[NODE];

    float v = x[t];
    red[t] = v;
    __syncthreads();
    #pragma unroll
    for (int s = 64; s > 0; s >>= 1) {
        if (t < s) red[t] += red[t + s];
        __syncthreads();
    }
    float mean = red[0] * (1.0f / NODE);
    float d = v - mean;
    __syncthreads();
    red[t] = d * d;
    __syncthreads();
    #pragma unroll
    for (int s = 64; s > 0; s >>= 1) {
        if (t < s) red[t] += red[t + s];
        __syncthreads();
    }
    float var = red[0] * (1.0f / NODE);
    float xn = d * rsqrtf(var + EPS) * lw[t] + lb[t];
    __syncthreads();
    sx[t] = xn;
    __syncthreads();

    // projection: 128 threads = 32 h x 4 segments of 32 c
    int h = t & 31, seg = t >> 5;
    const f32x4* wv = (const f32x4*)(W + h * NODE + seg * 32);
    const f32x4* xv = (const f32x4*)(sx + seg * 32);
    float acc = 0.f;
    #pragma unroll
    for (int z = 0; z < 8; ++z) {
        f32x4 a = wv[z], b = xv[z];
        acc += a[0]*b[0] + a[1]*b[1] + a[2]*b[2] + a[3]*b[3];
    }
    red[t] = acc;  // t == seg*32 + h
    __syncthreads();
    if (t < 32) {
        float y = red[t] + red[t + 32] + red[t + 64] + red[t + 96] + bb[t];
        yo[t] = (bf16_t)y;
    }
}

// ---------------- K2: S2[n = j*128+k][c] = sum_e c[j,e] * W3[k,c,e], bf16 out ----------------
// one block per k (128 blocks), one wave. GEMM M=128(j) x N=32(c), K=32(e): 8x2 MFMA tiles.
__global__ __launch_bounds__(64) void k2_s(
    const bf16_t* __restrict__ c_b, const float* __restrict__ W_out,
    bf16_t* __restrict__ S2)
{
    const int k = blockIdx.x;
    const int lane = threadIdx.x;
    const int q = lane >> 4, l16 = lane & 15;
    const float* Wrow = W_out + k * (HID * HID);

    f32x4 zacc = {0.f, 0.f, 0.f, 0.f};

    // B fragments: B[e][c] from W3[k][c][e] stored [c][e]-row-major (B^T layout)
    bf16x8 bfrag[2];
    #pragma unroll
    for (int nt = 0; nt < 2; ++nt) {
        int c = nt * 16 + l16;
        const float* wp = Wrow + c * 32 + q * 8;
        f32x4 w0 = *(const f32x4*)(wp);
        f32x4 w1 = *(const f32x4*)(wp + 4);
        bf16x8 bf;
        #pragma unroll
        for (int z = 0; z < 4; ++z) { bf[z] = (bf16_t)w0[z]; bf[z + 4] = (bf16_t)w1[z]; }
        bfrag[nt] = bf;
    }

    #pragma unroll
    for (int mt = 0; mt < 8; ++mt) {
        bf16x8 afrag = *(const bf16x8*)(c_b + (mt * 16 + l16) * 32 + q * 8);
        f32x4 acc0 = __builtin_amdgcn_mfma_f32_16x16x32_bf16(afrag, bfrag[0], zacc, 0, 0, 0);
        f32x4 acc1 = __builtin_amdgcn_mfma_f32_16x16x32_bf16(afrag, bfrag[1], zacc, 0, 0, 0);
        #pragma unroll
        for (int r = 0; r < 4; ++r) {
            int jrow = mt * 16 + q * 4 + r;
            S2[(jrow * 128 + k) * 32 + l16]      = (bf16_t)acc0[r];
            S2[(jrow * 128 + k) * 32 + 16 + l16] = (bf16_t)acc1[r];
        }
    }
}

// ---------------- K3: out[i, n] = sum_c p[i,c] * S2[n][c], + b_out[n&127], masked ----------------
// 2560 blocks x 256 thr; block tile 64i x 64n; wave tile 16i x 64n (4 MFMA).
__global__ __launch_bounds__(256) void k3_main(
    const bf16_t* __restrict__ p_b, const bf16_t* __restrict__ S2,
    const float* __restrict__ b_out,
    const int* __restrict__ p_mask, const int* __restrict__ c_mask,
    float* __restrict__ out)
{
    const int blk = blockIdx.x;
    const int bn = blk & 255;   // 256 n-tiles of 64
    const int bi = blk >> 8;    // 10 i-tiles of 64
    const int wave = threadIdx.x >> 6;
    const int lane = threadIdx.x & 63;
    const int q = lane >> 4, l16 = lane & 15;
    const int i0 = bi * 64 + wave * 16;
    const int n0 = bn * 64;

    f32x4 zacc = {0.f, 0.f, 0.f, 0.f};

    // A fragment: p rows, 8 consecutive k per lane = one 16B load
    bf16x8 afrag = *(const bf16x8*)(p_b + (i0 + l16) * 32 + q * 8);

    f32x4 acc[4];
    #pragma unroll
    for (int t = 0; t < 4; ++t) {
        bf16x8 bfrag = *(const bf16x8*)(S2 + (n0 + t * 16 + l16) * 32 + q * 8);
        acc[t] = __builtin_amdgcn_mfma_f32_16x16x32_bf16(afrag, bfrag, zacc, 0, 0, 0);
    }

    // epilogue: j is uniform per block (64-aligned n-tile within one j)
    const int j = n0 >> 7;
    const float cm = (c_mask[j] != 0) ? 1.f : 0.f;
    float pm[4];
    #pragma unroll
    for (int r = 0; r < 4; ++r)
        pm[r] = ((p_mask[i0 + q * 4 + r] != 0) ? 1.f : 0.f) * cm;

    #pragma unroll
    for (int t = 0; t < 4; ++t) {
        int n = n0 + t * 16 + l16;
        float bo = b_out[n & 127];
        #pragma unroll
        for (int r = 0; r < 4; ++r) {
            int i = i0 + q * 4 + r;
            out[i * (LC * PAIR) + n] = (acc[t][r] + bo) * pm[r];
        }
    }
}

extern "C" void kernel_launch(void* const* d_in, const int* in_sizes, int n_in,
                              void* d_out, int out_size, void* d_ws, size_t ws_size,
                              hipStream_t stream) {
    const float* p_embed = (const float*)d_in[0];
    const float* c_embed = (const float*)d_in[1];
    const int* p_mask = (const int*)d_in[2];
    const int* c_mask = (const int*)d_in[3];
    const float* ln_p_w = (const float*)d_in[4];
    const float* ln_p_b = (const float*)d_in[5];
    const float* ln_c_w = (const float*)d_in[6];
    const float* ln_c_b = (const float*)d_in[7];
    const float* W_p   = (const float*)d_in[8];
    const float* b_p   = (const float*)d_in[9];
    const float* W_c   = (const float*)d_in[10];
    const float* b_c   = (const float*)d_in[11];
    const float* W_out = (const float*)d_in[12];
    const float* b_out = (const float*)d_in[13];

    // workspace layout
    bf16_t* p_b = (bf16_t*)d_ws;                              // 640*32*2  = 40960 B
    bf16_t* c_b = (bf16_t*)((char*)d_ws + 40960);             // 128*32*2  = 8192 B
    bf16_t* S2  = (bf16_t*)((char*)d_ws + 49152);             // 16384*32*2 = 1 MiB

    float* out = (float*)d_out;
    float* mask_out = out + (size_t)LP * LC * PAIR;           // tuple output #2

    k1_rows<<<LP + LC + 320, 128, 0, stream>>>(
        p_embed, c_embed, p_mask, c_mask,
        ln_p_w, ln_p_b, ln_c_w, ln_c_b,
        W_p, b_p, W_c, b_c, p_b, c_b, mask_out);

    k2_s<<<PAIR, 64, 0, stream>>>(c_b, W_out, S2);

    k3_main<<<2560, 256, 0, stream>>>(p_b, S2, b_out, p_mask, c_mask, out);
}

// Round 3
// 103.777 us; speedup vs baseline: 1.0077x; 1.0077x over previous
//
#include <hip/hip_runtime.h>
#include <hip/hip_bf16.h>

#define LP   640
#define LC   128
#define NODE 128
#define HID  32
#define PAIR 128
#define EPS  1e-5f

typedef __bf16 bf16_t;
typedef __attribute__((ext_vector_type(8))) __bf16 bf16x8;
typedef __attribute__((ext_vector_type(4))) float f32x4;

// ---------------- K1: wave-per-row LayerNorm + projection, plus mask output ----------------
// blocks 0..191: 4 rows each (rows 0..639 = p, 640..767 = c)
// blocks 192..271: mask writes (1024 elems each, float4)
__global__ __launch_bounds__(256) void k1_rows(
    const float* __restrict__ p_embed, const float* __restrict__ c_embed,
    const int* __restrict__ p_mask, const int* __restrict__ c_mask,
    const float* __restrict__ ln_p_w, const float* __restrict__ ln_p_b,
    const float* __restrict__ ln_c_w, const float* __restrict__ ln_c_b,
    const float* __restrict__ W_p, const float* __restrict__ b_p,
    const float* __restrict__ W_c, const float* __restrict__ b_c,
    bf16_t* __restrict__ p_out, bf16_t* __restrict__ c_out,
    float* __restrict__ mask_out)
{
    const int blk = blockIdx.x;
    const int t = threadIdx.x;

    if (blk >= 192) {
        // mask blocks: 80 blocks x 1024 elems = 81920 = LP*LC
        int idx = (blk - 192) * 1024 + t * 4;
        int i = idx >> 7, j = idx & 127;
        float pm = (p_mask[i] != 0) ? 1.0f : 0.0f;
        f32x4 m;
        m[0] = pm * ((c_mask[j + 0] != 0) ? 1.0f : 0.0f);
        m[1] = pm * ((c_mask[j + 1] != 0) ? 1.0f : 0.0f);
        m[2] = pm * ((c_mask[j + 2] != 0) ? 1.0f : 0.0f);
        m[3] = pm * ((c_mask[j + 3] != 0) ? 1.0f : 0.0f);
        *(f32x4*)(mask_out + idx) = m;
        return;
    }

    const int wave = t >> 6;
    const int lane = t & 63;
    const int row = blk * 4 + wave;       // 0..767

    const float* x; const float* lw; const float* lb;
    const float* W; const float* bb; bf16_t* yo;
    if (row < LP) {
        x = p_embed + row * NODE; lw = ln_p_w; lb = ln_p_b;
        W = W_p; bb = b_p; yo = p_out + row * HID;
    } else {
        int r = row - LP;
        x = c_embed + r * NODE; lw = ln_c_w; lb = ln_c_b;
        W = W_c; bb = b_c; yo = c_out + r * HID;
    }

    __shared__ __align__(16) float sx[4][NODE];

    // LayerNorm: 2 elems/lane, fused sum+sumsq shuffle reduction
    float v0 = x[lane], v1 = x[lane + 64];
    float s  = v0 + v1;
    float ss = v0 * v0 + v1 * v1;
    #pragma unroll
    for (int off = 32; off > 0; off >>= 1) {
        s  += __shfl_xor(s, off);
        ss += __shfl_xor(ss, off);
    }
    float mean = s * (1.0f / NODE);
    float var  = ss * (1.0f / NODE) - mean * mean;
    float rs   = rsqrtf(var + EPS);
    sx[wave][lane]      = (v0 - mean) * rs * lw[lane]      + lb[lane];
    sx[wave][lane + 64] = (v1 - mean) * rs * lw[lane + 64] + lb[lane + 64];
    __syncthreads();   // intra-wave LDS visibility (cheap, uniform across row blocks)

    // projection: lane = half*32 + h; dot over 64 c's, then combine halves
    const int h = lane & 31, half = lane >> 5;
    const f32x4* wv = (const f32x4*)(W + h * NODE + half * 64);
    const f32x4* xv = (const f32x4*)(&sx[wave][half * 64]);
    float acc = 0.f;
    #pragma unroll
    for (int z = 0; z < 16; ++z) {
        f32x4 a = wv[z], b = xv[z];
        acc += a[0]*b[0] + a[1]*b[1] + a[2]*b[2] + a[3]*b[3];
    }
    acc += __shfl_xor(acc, 32);
    if (lane < 32) yo[h] = (bf16_t)(acc + bb[h]);
}

// ---------------- K2: S2[n = j*128+k][c] = sum_e c[j,e] * W3[k,c,e], bf16 out ----------------
// 512 blocks x 64 thr: block b -> k = b>>2, mt pair (b&3)*2.
__global__ __launch_bounds__(64) void k2_s(
    const bf16_t* __restrict__ c_b, const float* __restrict__ W_out,
    bf16_t* __restrict__ S2)
{
    const int k = blockIdx.x >> 2;
    const int mtbase = (blockIdx.x & 3) * 2;
    const int lane = threadIdx.x;
    const int q = lane >> 4, l16 = lane & 15;
    const float* Wrow = W_out + k * (HID * HID);

    f32x4 zacc = {0.f, 0.f, 0.f, 0.f};

    // B fragments: B[e][c] from W3[k][c][e] stored [c][e]-row-major
    bf16x8 bfrag[2];
    #pragma unroll
    for (int nt = 0; nt < 2; ++nt) {
        int c = nt * 16 + l16;
        const float* wp = Wrow + c * 32 + q * 8;
        f32x4 w0 = *(const f32x4*)(wp);
        f32x4 w1 = *(const f32x4*)(wp + 4);
        bf16x8 bf;
        #pragma unroll
        for (int z = 0; z < 4; ++z) { bf[z] = (bf16_t)w0[z]; bf[z + 4] = (bf16_t)w1[z]; }
        bfrag[nt] = bf;
    }

    #pragma unroll
    for (int mi = 0; mi < 2; ++mi) {
        int mt = mtbase + mi;
        bf16x8 afrag = *(const bf16x8*)(c_b + (mt * 16 + l16) * 32 + q * 8);
        f32x4 acc0 = __builtin_amdgcn_mfma_f32_16x16x32_bf16(afrag, bfrag[0], zacc, 0, 0, 0);
        f32x4 acc1 = __builtin_amdgcn_mfma_f32_16x16x32_bf16(afrag, bfrag[1], zacc, 0, 0, 0);
        #pragma unroll
        for (int r = 0; r < 4; ++r) {
            int jrow = mt * 16 + q * 4 + r;
            S2[(jrow * 128 + k) * 32 + l16]      = (bf16_t)acc0[r];
            S2[(jrow * 128 + k) * 32 + 16 + l16] = (bf16_t)acc1[r];
        }
    }
}

// ---------------- K3: out[i, n] = sum_c p[i,c] * S2[n][c], + b_out, masked ----------------
// 1280 blocks x 256 thr; block tile 64i x 128n (one j per block); wave tile 16i x 128n.
__global__ __launch_bounds__(256) void k3_main(
    const bf16_t* __restrict__ p_b, const bf16_t* __restrict__ S2,
    const float* __restrict__ b_out,
    const int* __restrict__ p_mask, const int* __restrict__ c_mask,
    float* __restrict__ out)
{
    const int blk = blockIdx.x;
    const int bn = blk & 127;   // 128 n-tiles of 128 (== j)
    const int bi = blk >> 7;    // 10 i-tiles of 64
    const int wave = threadIdx.x >> 6;
    const int lane = threadIdx.x & 63;
    const int q = lane >> 4, l16 = lane & 15;
    const int i0 = bi * 64 + wave * 16;
    const int n0 = bn * 128;

    f32x4 zacc = {0.f, 0.f, 0.f, 0.f};

    // A fragment: loaded once per wave
    bf16x8 afrag = *(const bf16x8*)(p_b + (i0 + l16) * 32 + q * 8);

    f32x4 acc[8];
    #pragma unroll
    for (int t = 0; t < 8; ++t) {
        bf16x8 bfrag = *(const bf16x8*)(S2 + (n0 + t * 16 + l16) * 32 + q * 8);
        acc[t] = __builtin_amdgcn_mfma_f32_16x16x32_bf16(afrag, bfrag, zacc, 0, 0, 0);
    }

    // epilogue: j uniform per block; n&127 == t*16+l16 since n0 is a multiple of 128
    const int j = bn;
    const float cm = (c_mask[j] != 0) ? 1.f : 0.f;
    float pm[4];
    #pragma unroll
    for (int r = 0; r < 4; ++r)
        pm[r] = ((p_mask[i0 + q * 4 + r] != 0) ? 1.f : 0.f) * cm;

    float bo[8];
    #pragma unroll
    for (int t = 0; t < 8; ++t) bo[t] = b_out[t * 16 + l16];

    #pragma unroll
    for (int t = 0; t < 8; ++t) {
        int n = n0 + t * 16 + l16;
        #pragma unroll
        for (int r = 0; r < 4; ++r) {
            int i = i0 + q * 4 + r;
            out[(size_t)i * (LC * PAIR) + n] = (acc[t][r] + bo[t]) * pm[r];
        }
    }
}

extern "C" void kernel_launch(void* const* d_in, const int* in_sizes, int n_in,
                              void* d_out, int out_size, void* d_ws, size_t ws_size,
                              hipStream_t stream) {
    const float* p_embed = (const float*)d_in[0];
    const float* c_embed = (const float*)d_in[1];
    const int* p_mask = (const int*)d_in[2];
    const int* c_mask = (const int*)d_in[3];
    const float* ln_p_w = (const float*)d_in[4];
    const float* ln_p_b = (const float*)d_in[5];
    const float* ln_c_w = (const float*)d_in[6];
    const float* ln_c_b = (const float*)d_in[7];
    const float* W_p   = (const float*)d_in[8];
    const float* b_p   = (const float*)d_in[9];
    const float* W_c   = (const float*)d_in[10];
    const float* b_c   = (const float*)d_in[11];
    const float* W_out = (const float*)d_in[12];
    const float* b_out = (const float*)d_in[13];

    // workspace layout
    bf16_t* p_b = (bf16_t*)d_ws;                              // 640*32*2  = 40960 B
    bf16_t* c_b = (bf16_t*)((char*)d_ws + 40960);             // 128*32*2  = 8192 B
    bf16_t* S2  = (bf16_t*)((char*)d_ws + 49152);             // 16384*32*2 = 1 MiB

    float* out = (float*)d_out;
    float* mask_out = out + (size_t)LP * LC * PAIR;           // tuple output #2

    k1_rows<<<272, 256, 0, stream>>>(
        p_embed, c_embed, p_mask, c_mask,
        ln_p_w, ln_p_b, ln_c_w, ln_c_b,
        W_p, b_p, W_c, b_c, p_b, c_b, mask_out);

    k2_s<<<512, 64, 0, stream>>>(c_b, W_out, S2);

    k3_main<<<1280, 256, 0, stream>>>(p_b, S2, b_out, p_mask, c_mask, out);
}